// Round 13
// baseline (11925.060 us; speedup 1.0000x reference)
//
#include <hip/hip_runtime.h>
#include <hip/hip_bf16.h>
#include <cstdint>
#include <cstddef>

#define NWG   256
#define NTH   512
#define LSTEP 1024
#define FAST_TRIES 4096

typedef __attribute__((ext_vector_type(8))) short short8;
typedef __attribute__((ext_vector_type(4))) float f32x4;
typedef __attribute__((ext_vector_type(4))) unsigned int u32x4;
typedef __attribute__((ext_vector_type(2))) unsigned int u32x2;

__device__ __forceinline__ unsigned f2bf_bits(float x) {
  __hip_bfloat16 h = __float2bfloat16(x);
  return (unsigned)__builtin_bit_cast(unsigned short, h);
}
__device__ __forceinline__ float bfbits2f(unsigned b) {
  return __bfloat162float(__builtin_bit_cast(__hip_bfloat16, (unsigned short)b));
}
__device__ __forceinline__ float ftanh(float x) {
  const float ax = fminf(fabsf(x), 15.f);
  const float e  = __expf(-2.f * ax);
  const float t  = (1.f - e) / (1.f + e);
  return copysignf(t, x);
}
__device__ __forceinline__ float fsig(float x) {
  const float xx = fmaxf(fminf(x, 30.f), -30.f);
  return 1.f / (1.f + __expf(-xx));
}

// ws: [0,1024) xcctab[wg] = 0x100|xcc  | [4096..) stateFA, stateFB, stateSA, stateSB (256KB each)
// Entry = {lo: pk (bf16 hi|lo), hi: tag}. State(S) tag = S+1, parity S&1.
// F = fast copy (plain stores, sc0 loads — valid only within one XCD's L2).
// S = safe copy (sc1 stores/loads via MALL — always correct; R10-proven).
// Waves poll F only if all 4 of their producers are physically same-XCD
// (HW_REG_XCC_ID equality), with a bounded-tries permanent demotion to S.
// Work mapping (bc=wg&7, jc=wg>>3) is logical — placement is ONLY a hint.

__global__ void __launch_bounds__(NTH, 2)
fused_scan(const float* __restrict__ u, const float* __restrict__ h0,
           const float* __restrict__ Wi, const float* __restrict__ bi,
           const float* __restrict__ Wm, const float* __restrict__ bm,
           float* __restrict__ out,
           unsigned long long* __restrict__ stateFA,
           unsigned long long* __restrict__ stateFB,
           unsigned long long* __restrict__ stateSA,
           unsigned long long* __restrict__ stateSB,
           unsigned* __restrict__ xcctab)
{
  __shared__ float part_s[5120];   // [kh8][r8][c80] me MFMA partials
  __shared__ float ie_part[3072];  // [kc4][r8][c96] ie MFMA partials
  __shared__ float hf_own[128];    // [r8][j16]
  __shared__ float hs_own[128];
  __shared__ float bm_s[80];
  __shared__ float bi_s[96];

  const int wg   = blockIdx.x;
  const int bc   = wg & 7;         // batch-group (XCD-local under round-robin)
  const int jc   = wg >> 3;        // 32 col-groups
  const int j0   = jc * 16;
  const int r0   = bc * 8;
  const int tid  = threadIdx.x;
  const int w    = tid >> 6;
  const int lane = tid & 63;
  const int colf = lane & 15;
  const int ksub = lane >> 4;
  const int rloc = lane & 7;

  // ---- publish my physical XCD id (hint table) ----
  unsigned my_xcc;
  asm volatile("s_getreg_b32 %0, hwreg(HW_REG_XCC_ID)" : "=s"(my_xcc));
  my_xcc &= 0xffu;
  if (tid == 0) {
    unsigned* tp = xcctab + wg;
    const unsigned v = 0x100u | my_xcc;
    asm volatile("global_store_dword %0, %1, off sc1" :: "v"(tp), "v"(v) : "memory");
  }

  // ---- one-time small LDS ----
  if (tid < 80) bm_s[tid] = bm[(tid % 5) * 512 + j0 + tid / 5];
  if (tid >= 128 && tid < 224) {
    const int c = tid - 128;
    bi_s[c] = bi[(c % 6) * 512 + j0 + c / 6];
  }
  // ---- init own hf/hs, publish State(0) with tag=1 (both copies) ----
  if (tid < 128) {
    const int r = tid >> 4, j16 = tid & 15;
    const float f = h0[(size_t)(r0 + r) * 512 + j0 + j16];
    const float s = h0[(size_t)32768 + (size_t)(r0 + r) * 512 + j0 + j16];
    hf_own[tid] = f;
    hs_own[tid] = s;
    const unsigned hb = f2bf_bits(f);
    const unsigned lb = f2bf_bits(f - bfbits2f(hb));
    u32x2 pr; pr[0] = hb | (lb << 16); pr[1] = 1u;
    const size_t eo = (size_t)(r0 + r) * 512 + j0 + j16;
    asm volatile("global_store_dwordx2 %0, %1, off"     :: "v"(stateFA + eo), "v"(pr) : "memory");
    asm volatile("global_store_dwordx2 %0, %1, off sc1" :: "v"(stateSA + eo), "v"(pr) : "memory");
  }

  // ---- per-wave locality decision: are my 4 producers on my XCD? ----
  bool fastmode;
  {
    unsigned pv = 0x100u | my_xcc;   // default (lanes >= 4): trivially equal
    if (lane < 4) {
      const unsigned* tp = xcctab + bc + (w * 4 + lane) * 8;
      for (;;) {
        unsigned v;
        asm volatile("global_load_dword %0, %1, off sc1" : "=&v"(v) : "v"(tp) : "memory");
        asm volatile("s_waitcnt vmcnt(0)" ::: "memory");
        __builtin_amdgcn_sched_barrier(0);
        if (v & 0x100u) { pv = v; break; }
        __builtin_amdgcn_s_sleep(1);
      }
    }
    fastmode = __all((pv & 0xffu) == my_xcc);
  }

  // ---- B-fragment gathers ----
  short8 bh[5][2], bl[5][2];
  #pragma unroll
  for (int nt = 0; nt < 5; ++nt) {
    const int c = nt * 16 + colf;
    const int gcol = (c % 5) * 512 + j0 + c / 5;
    #pragma unroll
    for (int kt = 0; kt < 2; ++kt) {
      #pragma unroll
      for (int j = 0; j < 8; ++j) {
        const int kg = w * 64 + kt * 32 + ksub * 8 + j;
        const float wv = Wm[(size_t)kg * 2560 + gcol];
        const unsigned hb = f2bf_bits(wv);
        bh[nt][kt][j] = (short)hb;
        bl[nt][kt][j] = (short)f2bf_bits(wv - bfbits2f(hb));
      }
    }
  }
  const int iekc = w & 3;
  const int ienh = w >> 2;
  short8 bih[3], bil[3];
  #pragma unroll
  for (int nt = 0; nt < 3; ++nt) {
    const int c = (ienh * 3 + nt) * 16 + colf;
    const int gcol = (c % 6) * 512 + j0 + c / 6;
    #pragma unroll
    for (int j = 0; j < 8; ++j) {
      const int kg = iekc * 32 + ksub * 8 + j;
      const float wv = Wi[(size_t)kg * 3072 + gcol];
      const unsigned hb = f2bf_bits(wv);
      bih[nt][j] = (short)hb;
      bil[nt][j] = (short)f2bf_bits(wv - bfbits2f(hb));
    }
  }

  const float* ubase = u + (size_t)(r0 + rloc) * 131072 + iekc * 32 + ksub * 8;

  // ---- ie math from prefetched registers ----
  auto ie_math = [&](float4 xa, float4 xb) {
    const float xv[8] = {xa.x, xa.y, xa.z, xa.w, xb.x, xb.y, xb.z, xb.w};
    short8 ah, al;
    #pragma unroll
    for (int j = 0; j < 8; ++j) {
      const unsigned hb = f2bf_bits(xv[j]);
      ah[j] = (short)hb;
      al[j] = (short)f2bf_bits(xv[j] - bfbits2f(hb));
    }
    f32x4 acc[3];
    #pragma unroll
    for (int nt = 0; nt < 3; ++nt) { acc[nt][0]=0.f; acc[nt][1]=0.f; acc[nt][2]=0.f; acc[nt][3]=0.f; }
    #pragma unroll
    for (int nt = 0; nt < 3; ++nt) {
      acc[nt] = __builtin_amdgcn_mfma_f32_16x16x32_bf16(ah, bih[nt], acc[nt], 0, 0, 0);
      acc[nt] = __builtin_amdgcn_mfma_f32_16x16x32_bf16(ah, bil[nt], acc[nt], 0, 0, 0);
      acc[nt] = __builtin_amdgcn_mfma_f32_16x16x32_bf16(al, bih[nt], acc[nt], 0, 0, 0);
    }
    if (lane < 32) {
      const int rb = (lane >> 4) * 4;
      #pragma unroll
      for (int nt = 0; nt < 3; ++nt)
        #pragma unroll
        for (int i = 0; i < 4; ++i)
          ie_part[iekc * 768 + (rb + i) * 96 + (ienh * 3 + nt) * 16 + colf] = acc[nt][i];
    }
  };

  // ---- ie(0) ----
  {
    const float4 xa0 = *(const float4*)ubase;
    const float4 xb0 = *(const float4*)(ubase + 4);
    ie_math(xa0, xb0);
  }

  const bool active = (lane & 8) == 0;   // fragment rows 8-15 are padding

  for (int st = 0; st < LSTEP; ++st) {
    const unsigned long long* __restrict__ scurF = (st & 1) ? stateFB : stateFA;
    unsigned long long* __restrict__ snxtF       = (st & 1) ? stateFA : stateFB;
    const unsigned long long* __restrict__ scurS = (st & 1) ? stateSB : stateSA;
    unsigned long long* __restrict__ snxtS       = (st & 1) ? stateSA : stateSB;

    // ======== phase 1: dual-path poll-with-payload, unpack, MFMA ========
    {
      const unsigned tag = (unsigned)(st + 1);
      const size_t eoff = (size_t)(r0 + rloc) * 512 + w * 64 + ksub * 8;
      u32x4 p0 = {0,0,0,0}, p1 = {0,0,0,0}, p2 = {0,0,0,0}, p3 = {0,0,0,0};
      u32x4 p4 = {0,0,0,0}, p5 = {0,0,0,0}, p6 = {0,0,0,0}, p7 = {0,0,0,0};
      if (active) {
#define READ8(PTR, FLAG, OKVAR)                                                                              \
        {                                                                                                    \
          asm volatile("global_load_dwordx4 %0, %1, off " FLAG            : "=&v"(p0) : "v"(PTR) : "memory"); \
          asm volatile("global_load_dwordx4 %0, %1, off offset:16 " FLAG  : "=&v"(p1) : "v"(PTR) : "memory"); \
          asm volatile("global_load_dwordx4 %0, %1, off offset:32 " FLAG  : "=&v"(p2) : "v"(PTR) : "memory"); \
          asm volatile("global_load_dwordx4 %0, %1, off offset:48 " FLAG  : "=&v"(p3) : "v"(PTR) : "memory"); \
          asm volatile("global_load_dwordx4 %0, %1, off offset:256 " FLAG : "=&v"(p4) : "v"(PTR) : "memory"); \
          asm volatile("global_load_dwordx4 %0, %1, off offset:272 " FLAG : "=&v"(p5) : "v"(PTR) : "memory"); \
          asm volatile("global_load_dwordx4 %0, %1, off offset:288 " FLAG : "=&v"(p6) : "v"(PTR) : "memory"); \
          asm volatile("global_load_dwordx4 %0, %1, off offset:304 " FLAG : "=&v"(p7) : "v"(PTR) : "memory"); \
          asm volatile("s_waitcnt vmcnt(0)" ::: "memory");                                                   \
          __builtin_amdgcn_sched_barrier(0);  /* rule #18 */                                                 \
          OKVAR = p0[1] >= tag && p0[3] >= tag && p1[1] >= tag && p1[3] >= tag                               \
               && p2[1] >= tag && p2[3] >= tag && p3[1] >= tag && p3[3] >= tag                               \
               && p4[1] >= tag && p4[3] >= tag && p5[1] >= tag && p5[3] >= tag                               \
               && p6[1] >= tag && p6[3] >= tag && p7[1] >= tag && p7[3] >= tag;                              \
        }
        bool got = false;
        if (fastmode) {
          const unsigned long long* baseF = scurF + eoff;
          int tries = 0;
          bool ok;
          do {
            READ8(baseF, "sc0", ok)
            if (__all(ok)) { got = true; break; }
            ++tries;
          } while (tries < FAST_TRIES);
          if (!got) fastmode = false;   // permanent demotion — never deadlocks
        }
        if (!got) {
          const unsigned long long* baseS = scurS + eoff;
          for (;;) {
            bool ok;
            READ8(baseS, "sc1", ok)
            if (__all(ok)) break;
            __builtin_amdgcn_s_sleep(1);
          }
        }
#undef READ8
      }
      __builtin_amdgcn_sched_barrier(0);
      short8 ah[2], al[2];
      ah[0][0] = (short)(p0[0] & 0xffffu); al[0][0] = (short)(p0[0] >> 16);
      ah[0][1] = (short)(p0[2] & 0xffffu); al[0][1] = (short)(p0[2] >> 16);
      ah[0][2] = (short)(p1[0] & 0xffffu); al[0][2] = (short)(p1[0] >> 16);
      ah[0][3] = (short)(p1[2] & 0xffffu); al[0][3] = (short)(p1[2] >> 16);
      ah[0][4] = (short)(p2[0] & 0xffffu); al[0][4] = (short)(p2[0] >> 16);
      ah[0][5] = (short)(p2[2] & 0xffffu); al[0][5] = (short)(p2[2] >> 16);
      ah[0][6] = (short)(p3[0] & 0xffffu); al[0][6] = (short)(p3[0] >> 16);
      ah[0][7] = (short)(p3[2] & 0xffffu); al[0][7] = (short)(p3[2] >> 16);
      ah[1][0] = (short)(p4[0] & 0xffffu); al[1][0] = (short)(p4[0] >> 16);
      ah[1][1] = (short)(p4[2] & 0xffffu); al[1][1] = (short)(p4[2] >> 16);
      ah[1][2] = (short)(p5[0] & 0xffffu); al[1][2] = (short)(p5[0] >> 16);
      ah[1][3] = (short)(p5[2] & 0xffffu); al[1][3] = (short)(p5[2] >> 16);
      ah[1][4] = (short)(p6[0] & 0xffffu); al[1][4] = (short)(p6[0] >> 16);
      ah[1][5] = (short)(p6[2] & 0xffffu); al[1][5] = (short)(p6[2] >> 16);
      ah[1][6] = (short)(p7[0] & 0xffffu); al[1][6] = (short)(p7[0] >> 16);
      ah[1][7] = (short)(p7[2] & 0xffffu); al[1][7] = (short)(p7[2] >> 16);
      f32x4 acc[5];
      #pragma unroll
      for (int nt = 0; nt < 5; ++nt) { acc[nt][0]=0.f; acc[nt][1]=0.f; acc[nt][2]=0.f; acc[nt][3]=0.f; }
      #pragma unroll
      for (int nt = 0; nt < 5; ++nt)
        #pragma unroll
        for (int kt = 0; kt < 2; ++kt) {
          acc[nt] = __builtin_amdgcn_mfma_f32_16x16x32_bf16(ah[kt], bh[nt][kt], acc[nt], 0, 0, 0);
          acc[nt] = __builtin_amdgcn_mfma_f32_16x16x32_bf16(ah[kt], bl[nt][kt], acc[nt], 0, 0, 0);
          acc[nt] = __builtin_amdgcn_mfma_f32_16x16x32_bf16(al[kt], bh[nt][kt], acc[nt], 0, 0, 0);
        }
      if (lane < 32) {
        const int rb = (lane >> 4) * 4;
        #pragma unroll
        for (int nt = 0; nt < 5; ++nt)
          #pragma unroll
          for (int i = 0; i < 4; ++i)
            part_s[(w * 8 + rb + i) * 80 + nt * 16 + colf] = acc[nt][i];
      }
    }
    __syncthreads();   // sync #1 — part_s/ie_part complete for step st

    // ---- prefetch u(st+1) ----
    float4 xa = {0.f, 0.f, 0.f, 0.f}, xb = {0.f, 0.f, 0.f, 0.f};
    if (st + 1 < LSTEP) {
      const float* up = ubase + (size_t)(st + 1) * 128;
      xa = *(const float4*)up;
      xb = *(const float4*)(up + 4);
    }

    // ======== phase 2: fused reduce + gates + dual tagged publish ========
    if (tid < 128) {
      const int r = tid >> 4, j16 = tid & 15;
      float m[5];
      #pragma unroll
      for (int g = 0; g < 5; ++g) {
        float v = bm_s[j16 * 5 + g];
        #pragma unroll
        for (int kh = 0; kh < 8; ++kh) v += part_s[kh * 640 + r * 80 + j16 * 5 + g];
        m[g] = v;
      }
      float iacc[6];
      #pragma unroll
      for (int g = 0; g < 6; ++g) {
        float v = bi_s[j16 * 6 + g];
        #pragma unroll
        for (int kc = 0; kc < 4; ++kc) v += ie_part[kc * 768 + r * 96 + j16 * 6 + g];
        iacc[g] = v;
      }
      const float hf = hf_own[tid];
      const float hs = hs_own[tid];
      const float a = 1.f + ftanh(iacc[0] + m[0]);
      const float b = 1.5f * (1.f + ftanh(iacc[1] + m[1]));
      const float c = 0.3f + 0.7f * fsig(iacc[2] + m[2]);
      const float d = 0.03f * fsig(iacc[3] + m[3]);
      const float e = 1.f + fsig(iacc[4] + m[4]);
      const float hfn_v = (1.f - c) * hf + c * ftanh(iacc[5] + (a + b * hf * hf - hs) * hf);
      const float eh  = e * hf;
      const float eh2 = eh * eh;
      const float hsn_v = hs * (1.f - d) + d * eh2 * eh2;
      hf_own[tid] = hfn_v;
      hs_own[tid] = hsn_v;
      const unsigned hb = f2bf_bits(hfn_v);
      const unsigned lb = f2bf_bits(hfn_v - bfbits2f(hb));
      u32x2 pr; pr[0] = hb | (lb << 16); pr[1] = (unsigned)(st + 2);
      const size_t eo = (size_t)(r0 + r) * 512 + j0 + j16;
      asm volatile("global_store_dwordx2 %0, %1, off"     :: "v"(snxtF + eo), "v"(pr) : "memory");
      asm volatile("global_store_dwordx2 %0, %1, off sc1" :: "v"(snxtS + eo), "v"(pr) : "memory");
      out[(size_t)(r0 + r) * 524288 + (size_t)st * 512 + j0 + j16] = hfn_v;
      if (st == LSTEP - 1)
        out[(size_t)33554432 + (size_t)(r0 + r) * 512 + j0 + j16] = hfn_v;
    }
    __syncthreads();   // sync #2 — part_s/ie_part free for reuse
    if (st + 1 < LSTEP) ie_math(xa, xb);   // ie_part for st+1
  }
}

extern "C" void kernel_launch(void* const* d_in, const int* in_sizes, int n_in,
                              void* d_out, int out_size, void* d_ws, size_t ws_size,
                              hipStream_t stream) {
  (void)in_sizes; (void)n_in; (void)out_size; (void)ws_size;
  const float* u  = (const float*)d_in[0];
  const float* h0 = (const float*)d_in[1];
  const float* Wi = (const float*)d_in[2];
  const float* bi = (const float*)d_in[3];
  const float* Wm = (const float*)d_in[4];
  const float* bm = (const float*)d_in[5];
  float* out = (float*)d_out;
  unsigned* xcctab = (unsigned*)d_ws;                        // [0, 1024)
  char* sb = (char*)d_ws + 4096;
  unsigned long long* stateFA = (unsigned long long*)(sb);
  unsigned long long* stateFB = (unsigned long long*)(sb + 262144);
  unsigned long long* stateSA = (unsigned long long*)(sb + 2 * 262144);
  unsigned long long* stateSB = (unsigned long long*)(sb + 3 * 262144);
  // zero xcctab + all four state buffers (tags) every launch/replay
  hipMemsetAsync(d_ws, 0, 4096 + 4 * 262144, stream);
  hipLaunchKernelGGL(fused_scan, dim3(NWG), dim3(NTH), 0, stream,
                     u, h0, Wi, bi, Wm, bm, out,
                     stateFA, stateFB, stateSA, stateSB, xcctab);
}

// Round 15
// 3474.267 us; speedup vs baseline: 3.4324x; 3.4324x over previous
//
#include <hip/hip_runtime.h>
#include <hip/hip_bf16.h>
#include <cstdint>
#include <cstddef>

#define NWG   256
#define NTH   512
#define LSTEP 1024

typedef __attribute__((ext_vector_type(8))) short short8;
typedef __attribute__((ext_vector_type(4))) float f32x4;
typedef __attribute__((ext_vector_type(4))) unsigned int u32x4;

__device__ __forceinline__ unsigned f2bf_bits(float x) {
  __hip_bfloat16 h = __float2bfloat16(x);
  return (unsigned)__builtin_bit_cast(unsigned short, h);
}
__device__ __forceinline__ float bfbits2f(unsigned b) {
  return __bfloat162float(__builtin_bit_cast(__hip_bfloat16, (unsigned short)b));
}
__device__ __forceinline__ float ftanh(float x) {
  const float ax = fminf(fabsf(x), 15.f);
  const float e  = __expf(-2.f * ax);
  const float t  = (1.f - e) / (1.f + e);
  return copysignf(t, x);
}
__device__ __forceinline__ float fsig(float x) {
  const float xx = fmaxf(fminf(x, 30.f), -30.f);
  return 1.f / (1.f + __expf(-xx));
}

// ws: stateA u32[64*512] (128KB) | stateB u32[64*512]
// Entry = fp32_bits(hf) with the 3 mantissa LSBs replaced by tag3.
// Reconstruction error ~2^-21 relative — negligible vs the 8.3e-3 bf16-split
// baseline (R14's lo-plane truncation at ~2^-13 was NOT — fixed here).
// State(S): tag3 = (S+1)&7, buffer parity S&1. Same-buffer successive states
// differ by 2 mod 8 and lag is bounded by 1, so 3 bits disambiguate; first
// tag-0 poll (State(7)) happens after >=3 rewrites of that buffer, so the
// memset-0 value can never false-positive. Single 4B store per entry =
// single-copy atomic; poll==payload in one MALL RT. Consumers do the bf16
// hi/lo split in VALU after the poll (VALU idle there anyway).
// Grid decode: bc = wg & 7 (XCD-local group), jc = wg >> 3.

__global__ void __launch_bounds__(NTH, 2)
fused_scan(const float* __restrict__ u, const float* __restrict__ h0,
           const float* __restrict__ Wi, const float* __restrict__ bi,
           const float* __restrict__ Wm, const float* __restrict__ bm,
           float* __restrict__ out, unsigned* __restrict__ stateA,
           unsigned* __restrict__ stateB)
{
  __shared__ float part_s[5120];   // [kh8][r8][c80] me MFMA partials
  __shared__ float ie_part[3072];  // [kc4][r8][c96] ie MFMA partials
  __shared__ float hf_own[128];    // [r8][j16]
  __shared__ float hs_own[128];
  __shared__ float bm_s[80];
  __shared__ float bi_s[96];

  const int wg   = blockIdx.x;
  const int bc   = wg & 7;         // batch-group: same-XCD under round-robin
  const int jc   = wg >> 3;        // 32 col-groups
  const int j0   = jc * 16;
  const int r0   = bc * 8;
  const int tid  = threadIdx.x;
  const int w    = tid >> 6;
  const int lane = tid & 63;
  const int colf = lane & 15;
  const int ksub = lane >> 4;
  const int rloc = lane & 7;

  // ---- one-time small LDS ----
  if (tid < 80) bm_s[tid] = bm[(tid % 5) * 512 + j0 + tid / 5];
  if (tid >= 128 && tid < 224) {
    const int c = tid - 128;
    bi_s[c] = bi[(c % 6) * 512 + j0 + c / 6];
  }
  // ---- init own hf/hs, publish State(0) with tag3=1 ----
  if (tid < 128) {
    const int r = tid >> 4, j16 = tid & 15;
    const float f = h0[(size_t)(r0 + r) * 512 + j0 + j16];
    const float s = h0[(size_t)32768 + (size_t)(r0 + r) * 512 + j0 + j16];
    hf_own[tid] = f;
    hs_own[tid] = s;
    const unsigned pk = (__builtin_bit_cast(unsigned, f) & 0xfffffff8u) | 1u;
    unsigned* dst = stateA + (size_t)(r0 + r) * 512 + j0 + j16;
    asm volatile("global_store_dword %0, %1, off sc1" :: "v"(dst), "v"(pk) : "memory");
  }

  // ---- B-fragment gathers ----
  short8 bh[5][2], bl[5][2];
  #pragma unroll
  for (int nt = 0; nt < 5; ++nt) {
    const int c = nt * 16 + colf;
    const int gcol = (c % 5) * 512 + j0 + c / 5;
    #pragma unroll
    for (int kt = 0; kt < 2; ++kt) {
      #pragma unroll
      for (int j = 0; j < 8; ++j) {
        const int kg = w * 64 + kt * 32 + ksub * 8 + j;
        const float wv = Wm[(size_t)kg * 2560 + gcol];
        const unsigned hb = f2bf_bits(wv);
        bh[nt][kt][j] = (short)hb;
        bl[nt][kt][j] = (short)f2bf_bits(wv - bfbits2f(hb));
      }
    }
  }
  const int iekc = w & 3;
  const int ienh = w >> 2;
  short8 bih[3], bil[3];
  #pragma unroll
  for (int nt = 0; nt < 3; ++nt) {
    const int c = (ienh * 3 + nt) * 16 + colf;
    const int gcol = (c % 6) * 512 + j0 + c / 6;
    #pragma unroll
    for (int j = 0; j < 8; ++j) {
      const int kg = iekc * 32 + ksub * 8 + j;
      const float wv = Wi[(size_t)kg * 3072 + gcol];
      const unsigned hb = f2bf_bits(wv);
      bih[nt][j] = (short)hb;
      bil[nt][j] = (short)f2bf_bits(wv - bfbits2f(hb));
    }
  }

  const float* ubase = u + (size_t)(r0 + rloc) * 131072 + iekc * 32 + ksub * 8;

  // ---- ie math from prefetched registers ----
  auto ie_math = [&](float4 xa_, float4 xb_) {
    const float xv[8] = {xa_.x, xa_.y, xa_.z, xa_.w, xb_.x, xb_.y, xb_.z, xb_.w};
    short8 ah, al;
    #pragma unroll
    for (int j = 0; j < 8; ++j) {
      const unsigned hb = f2bf_bits(xv[j]);
      ah[j] = (short)hb;
      al[j] = (short)f2bf_bits(xv[j] - bfbits2f(hb));
    }
    f32x4 acc[3];
    #pragma unroll
    for (int nt = 0; nt < 3; ++nt) { acc[nt][0]=0.f; acc[nt][1]=0.f; acc[nt][2]=0.f; acc[nt][3]=0.f; }
    #pragma unroll
    for (int nt = 0; nt < 3; ++nt) {
      acc[nt] = __builtin_amdgcn_mfma_f32_16x16x32_bf16(ah, bih[nt], acc[nt], 0, 0, 0);
      acc[nt] = __builtin_amdgcn_mfma_f32_16x16x32_bf16(ah, bil[nt], acc[nt], 0, 0, 0);
      acc[nt] = __builtin_amdgcn_mfma_f32_16x16x32_bf16(al, bih[nt], acc[nt], 0, 0, 0);
    }
    if (lane < 32) {
      const int rb = (lane >> 4) * 4;
      #pragma unroll
      for (int nt = 0; nt < 3; ++nt)
        #pragma unroll
        for (int i = 0; i < 4; ++i)
          ie_part[iekc * 768 + (rb + i) * 96 + (ienh * 3 + nt) * 16 + colf] = acc[nt][i];
    }
  };

  // ---- ie(0) (prologue) ----
  {
    const float4 xa0 = *(const float4*)ubase;
    const float4 xb0 = *(const float4*)(ubase + 4);
    ie_math(xa0, xb0);
  }

  const bool active = (lane & 8) == 0;   // fragment rows 8-15 are padding
  float4 xa = {0.f, 0.f, 0.f, 0.f}, xb = {0.f, 0.f, 0.f, 0.f};  // u(st+1) carry

  for (int st = 0; st < LSTEP; ++st) {
    const unsigned* __restrict__ scur = (st & 1) ? stateB : stateA;
    unsigned* __restrict__ snxt       = (st & 1) ? stateA : stateB;

    // ======== phase 1: poll-with-payload (4B entries), split, MFMA ========
    {
      const unsigned tag3 = (unsigned)(st + 1) & 7u;
      const unsigned* base = scur + (size_t)(r0 + rloc) * 512 + w * 64 + ksub * 8;
      u32x4 q0 = {0,0,0,0}, q1 = {0,0,0,0}, q2 = {0,0,0,0}, q3 = {0,0,0,0};
      if (active) {
        for (;;) {
          asm volatile("global_load_dwordx4 %0, %1, off sc1"            : "=&v"(q0) : "v"(base) : "memory");
          asm volatile("global_load_dwordx4 %0, %1, off offset:16 sc1"  : "=&v"(q1) : "v"(base) : "memory");
          asm volatile("global_load_dwordx4 %0, %1, off offset:128 sc1" : "=&v"(q2) : "v"(base) : "memory");
          asm volatile("global_load_dwordx4 %0, %1, off offset:144 sc1" : "=&v"(q3) : "v"(base) : "memory");
          asm volatile("s_waitcnt vmcnt(0)" ::: "memory");
          // rule #18: pin the register-only tag compare AFTER the waitcnt.
          __builtin_amdgcn_sched_barrier(0);
          const bool ok =
              (q0[0] & 7u) == tag3 && (q0[1] & 7u) == tag3 && (q0[2] & 7u) == tag3 && (q0[3] & 7u) == tag3 &&
              (q1[0] & 7u) == tag3 && (q1[1] & 7u) == tag3 && (q1[2] & 7u) == tag3 && (q1[3] & 7u) == tag3 &&
              (q2[0] & 7u) == tag3 && (q2[1] & 7u) == tag3 && (q2[2] & 7u) == tag3 && (q2[3] & 7u) == tag3 &&
              (q3[0] & 7u) == tag3 && (q3[1] & 7u) == tag3 && (q3[2] & 7u) == tag3 && (q3[3] & 7u) == tag3;
          if (__all(ok)) break;
          __builtin_amdgcn_s_sleep(1);
        }
      }
      __builtin_amdgcn_sched_barrier(0);
      short8 ah[2], al[2];
      #pragma unroll
      for (int j = 0; j < 4; ++j) {
        {
          const float x0 = __builtin_bit_cast(float, q0[j] & 0xfffffff8u);
          const unsigned h0b = f2bf_bits(x0);
          ah[0][j] = (short)h0b;
          al[0][j] = (short)f2bf_bits(x0 - bfbits2f(h0b));
          const float x1 = __builtin_bit_cast(float, q1[j] & 0xfffffff8u);
          const unsigned h1b = f2bf_bits(x1);
          ah[0][j + 4] = (short)h1b;
          al[0][j + 4] = (short)f2bf_bits(x1 - bfbits2f(h1b));
          const float x2 = __builtin_bit_cast(float, q2[j] & 0xfffffff8u);
          const unsigned h2b = f2bf_bits(x2);
          ah[1][j] = (short)h2b;
          al[1][j] = (short)f2bf_bits(x2 - bfbits2f(h2b));
          const float x3 = __builtin_bit_cast(float, q3[j] & 0xfffffff8u);
          const unsigned h3b = f2bf_bits(x3);
          ah[1][j + 4] = (short)h3b;
          al[1][j + 4] = (short)f2bf_bits(x3 - bfbits2f(h3b));
        }
      }
      f32x4 acc[5];
      #pragma unroll
      for (int nt = 0; nt < 5; ++nt) { acc[nt][0]=0.f; acc[nt][1]=0.f; acc[nt][2]=0.f; acc[nt][3]=0.f; }
      #pragma unroll
      for (int nt = 0; nt < 5; ++nt)
        #pragma unroll
        for (int kt = 0; kt < 2; ++kt) {
          acc[nt] = __builtin_amdgcn_mfma_f32_16x16x32_bf16(ah[kt], bh[nt][kt], acc[nt], 0, 0, 0);
          acc[nt] = __builtin_amdgcn_mfma_f32_16x16x32_bf16(ah[kt], bl[nt][kt], acc[nt], 0, 0, 0);
          acc[nt] = __builtin_amdgcn_mfma_f32_16x16x32_bf16(al[kt], bh[nt][kt], acc[nt], 0, 0, 0);
        }
      if (lane < 32) {
        const int rb = (lane >> 4) * 4;
        #pragma unroll
        for (int nt = 0; nt < 5; ++nt)
          #pragma unroll
          for (int i = 0; i < 4; ++i)
            part_s[(w * 8 + rb + i) * 80 + nt * 16 + colf] = acc[nt][i];
      }
    }
    // ---- ie_part for step st (off the pre-poll critical path) ----
    if (st >= 1) ie_math(xa, xb);
    __syncthreads();   // sync #1 — part_s/ie_part complete for step st

    // ---- prefetch u(st+1) (consumed by ie_math inside phase1(st+1)) ----
    if (st + 1 < LSTEP) {
      const float* up = ubase + (size_t)(st + 1) * 128;
      xa = *(const float4*)up;
      xb = *(const float4*)(up + 4);
    }

    // ======== phase 2: fused reduce + gates + tagged publish ========
    if (tid < 128) {
      const int r = tid >> 4, j16 = tid & 15;
      float m[5];
      #pragma unroll
      for (int g = 0; g < 5; ++g) {
        float v = bm_s[j16 * 5 + g];
        #pragma unroll
        for (int kh = 0; kh < 8; ++kh) v += part_s[kh * 640 + r * 80 + j16 * 5 + g];
        m[g] = v;
      }
      float iacc[6];
      #pragma unroll
      for (int g = 0; g < 6; ++g) {
        float v = bi_s[j16 * 6 + g];
        #pragma unroll
        for (int kc = 0; kc < 4; ++kc) v += ie_part[kc * 768 + r * 96 + j16 * 6 + g];
        iacc[g] = v;
      }
      const float hf = hf_own[tid];
      const float hs = hs_own[tid];
      const float a = 1.f + ftanh(iacc[0] + m[0]);
      const float b = 1.5f * (1.f + ftanh(iacc[1] + m[1]));
      const float c = 0.3f + 0.7f * fsig(iacc[2] + m[2]);
      const float d = 0.03f * fsig(iacc[3] + m[3]);
      const float e = 1.f + fsig(iacc[4] + m[4]);
      const float hfn_v = (1.f - c) * hf + c * ftanh(iacc[5] + (a + b * hf * hf - hs) * hf);
      const float eh  = e * hf;
      const float eh2 = eh * eh;
      const float hsn_v = hs * (1.f - d) + d * eh2 * eh2;
      hf_own[tid] = hfn_v;
      hs_own[tid] = hsn_v;
      const unsigned pk = (__builtin_bit_cast(unsigned, hfn_v) & 0xfffffff8u)
                        | ((unsigned)(st + 2) & 7u);
      unsigned* dst = snxt + (size_t)(r0 + r) * 512 + j0 + j16;
      asm volatile("global_store_dword %0, %1, off sc1" :: "v"(dst), "v"(pk) : "memory");
      out[(size_t)(r0 + r) * 524288 + (size_t)st * 512 + j0 + j16] = hfn_v;
      if (st == LSTEP - 1)
        out[(size_t)33554432 + (size_t)(r0 + r) * 512 + j0 + j16] = hfn_v;
    }
    __syncthreads();   // sync #2 — part_s/ie_part free; poll(st+1) starts now
  }
}

extern "C" void kernel_launch(void* const* d_in, const int* in_sizes, int n_in,
                              void* d_out, int out_size, void* d_ws, size_t ws_size,
                              hipStream_t stream) {
  (void)in_sizes; (void)n_in; (void)out_size; (void)ws_size;
  const float* u  = (const float*)d_in[0];
  const float* h0 = (const float*)d_in[1];
  const float* Wi = (const float*)d_in[2];
  const float* bi = (const float*)d_in[3];
  const float* Wm = (const float*)d_in[4];
  const float* bm = (const float*)d_in[5];
  float* out = (float*)d_out;
  unsigned* stateA = (unsigned*)d_ws;
  unsigned* stateB = stateA + 64 * 512;
  hipMemsetAsync(d_ws, 0, 2 * 64 * 512 * 4, stream);  // zero tags both buffers
  hipLaunchKernelGGL(fused_scan, dim3(NWG), dim3(NTH), 0, stream,
                     u, h0, Wi, bi, Wm, bm, out, stateA, stateB);
}

// Round 16
// 2901.961 us; speedup vs baseline: 4.1093x; 1.1972x over previous
//
#include <hip/hip_runtime.h>
#include <hip/hip_bf16.h>
#include <cstdint>
#include <cstddef>

#define NWG   256
#define NTH   512
#define LSTEP 1024
#define FAST_TRIES 256

typedef __attribute__((ext_vector_type(8))) short short8;
typedef __attribute__((ext_vector_type(4))) float f32x4;
typedef __attribute__((ext_vector_type(4))) unsigned int u32x4;
typedef __attribute__((ext_vector_type(2))) unsigned int u32x2;

__device__ __forceinline__ unsigned f2bf_bits(float x) {
  __hip_bfloat16 h = __float2bfloat16(x);
  return (unsigned)__builtin_bit_cast(unsigned short, h);
}
__device__ __forceinline__ float bfbits2f(unsigned b) {
  return __bfloat162float(__builtin_bit_cast(__hip_bfloat16, (unsigned short)b));
}
__device__ __forceinline__ float ftanh(float x) {
  const float ax = fminf(fabsf(x), 15.f);
  const float e  = __expf(-2.f * ax);
  const float t  = (1.f - e) / (1.f + e);
  return copysignf(t, x);
}
__device__ __forceinline__ float fsig(float x) {
  const float xx = fmaxf(fminf(x, 30.f), -30.f);
  return 1.f / (1.f + __expf(-xx));
}

// ws: [0,1024) xcctab[wg]=0x100|xcc | [4096..) stateFA,FB,SA,SB (256KB each)
// Entry = {lo: pk (bf16 hi|lo), hi: tag}. State(S) tag=S+1, parity S&1.
// R10 protocol (verified 2961us) + dual-copy exchange:
//   F = fast copy: plain write-through stores + NT loads. nt = no-allocate,
//       and since no state access ever allocates in L1 (stores are
//       write-through/no-allocate, all reads nt), nt loads are served by the
//       shared per-XCD L2 (~200cy) — NOT stale L1 (R13's sc0 bug: sc0 =
//       workgroup scope = L1-cacheable = stale spins).
//   S = safe copy: sc1 via MALL — byte-identical to R10, always correct.
// Fast path only for waves whose 4 producers share this WG's XCC_ID
// (physical gate), with bounded-tries PERMANENT demotion => no deadlock,
// worst case == R10. Lag-1 + tag-verify carry over verbatim.
// Grid decode: bc = wg & 7 (XCD-local under round-robin), jc = wg >> 3.

__global__ void __launch_bounds__(NTH, 2)
fused_scan(const float* __restrict__ u, const float* __restrict__ h0,
           const float* __restrict__ Wi, const float* __restrict__ bi,
           const float* __restrict__ Wm, const float* __restrict__ bm,
           float* __restrict__ out,
           unsigned long long* __restrict__ stateFA,
           unsigned long long* __restrict__ stateFB,
           unsigned long long* __restrict__ stateSA,
           unsigned long long* __restrict__ stateSB,
           unsigned* __restrict__ xcctab)
{
  __shared__ float part_s[5120];   // [kh8][r8][c80] me MFMA partials
  __shared__ float ie_part[3072];  // [kc4][r8][c96] ie MFMA partials
  __shared__ float hf_own[128];    // [r8][j16]
  __shared__ float hs_own[128];
  __shared__ float bm_s[80];
  __shared__ float bi_s[96];

  const int wg   = blockIdx.x;
  const int bc   = wg & 7;         // batch-group: same-XCD under round-robin
  const int jc   = wg >> 3;        // 32 col-groups
  const int j0   = jc * 16;
  const int r0   = bc * 8;
  const int tid  = threadIdx.x;
  const int w    = tid >> 6;
  const int lane = tid & 63;
  const int colf = lane & 15;
  const int ksub = lane >> 4;
  const int rloc = lane & 7;

  // ---- publish my physical XCD id (hint table; R13-proven) ----
  unsigned my_xcc;
  asm volatile("s_getreg_b32 %0, hwreg(HW_REG_XCC_ID)" : "=s"(my_xcc));
  my_xcc &= 0xffu;
  if (tid == 0) {
    unsigned* tp = xcctab + wg;
    const unsigned v = 0x100u | my_xcc;
    asm volatile("global_store_dword %0, %1, off sc1" :: "v"(tp), "v"(v) : "memory");
  }

  // ---- one-time small LDS ----
  if (tid < 80) bm_s[tid] = bm[(tid % 5) * 512 + j0 + tid / 5];
  if (tid >= 128 && tid < 224) {
    const int c = tid - 128;
    bi_s[c] = bi[(c % 6) * 512 + j0 + c / 6];
  }
  // ---- init own hf/hs, publish State(0) with tag=1 (both copies) ----
  if (tid < 128) {
    const int r = tid >> 4, j16 = tid & 15;
    const float f = h0[(size_t)(r0 + r) * 512 + j0 + j16];
    const float s = h0[(size_t)32768 + (size_t)(r0 + r) * 512 + j0 + j16];
    hf_own[tid] = f;
    hs_own[tid] = s;
    const unsigned hb = f2bf_bits(f);
    const unsigned lb = f2bf_bits(f - bfbits2f(hb));
    u32x2 pr; pr[0] = hb | (lb << 16); pr[1] = 1u;
    const size_t eo = (size_t)(r0 + r) * 512 + j0 + j16;
    asm volatile("global_store_dwordx2 %0, %1, off"     :: "v"(stateFA + eo), "v"(pr) : "memory");
    asm volatile("global_store_dwordx2 %0, %1, off sc1" :: "v"(stateSA + eo), "v"(pr) : "memory");
  }

  // ---- per-wave locality gate: are my 4 producers on my XCD? ----
  bool fastmode;
  {
    unsigned pv = 0x100u | my_xcc;   // lanes >= 4: trivially equal
    if (lane < 4) {
      const unsigned* tp = xcctab + bc + (w * 4 + lane) * 8;
      for (;;) {
        unsigned v;
        asm volatile("global_load_dword %0, %1, off sc1" : "=&v"(v) : "v"(tp) : "memory");
        asm volatile("s_waitcnt vmcnt(0)" ::: "memory");
        __builtin_amdgcn_sched_barrier(0);
        if (v & 0x100u) { pv = v; break; }
        __builtin_amdgcn_s_sleep(1);
      }
    }
    fastmode = __all((pv & 0xffu) == my_xcc);
  }

  // ---- B-fragment gathers ----
  short8 bh[5][2], bl[5][2];
  #pragma unroll
  for (int nt = 0; nt < 5; ++nt) {
    const int c = nt * 16 + colf;
    const int gcol = (c % 5) * 512 + j0 + c / 5;
    #pragma unroll
    for (int kt = 0; kt < 2; ++kt) {
      #pragma unroll
      for (int j = 0; j < 8; ++j) {
        const int kg = w * 64 + kt * 32 + ksub * 8 + j;
        const float wv = Wm[(size_t)kg * 2560 + gcol];
        const unsigned hb = f2bf_bits(wv);
        bh[nt][kt][j] = (short)hb;
        bl[nt][kt][j] = (short)f2bf_bits(wv - bfbits2f(hb));
      }
    }
  }
  const int iekc = w & 3;
  const int ienh = w >> 2;
  short8 bih[3], bil[3];
  #pragma unroll
  for (int nt = 0; nt < 3; ++nt) {
    const int c = (ienh * 3 + nt) * 16 + colf;
    const int gcol = (c % 6) * 512 + j0 + c / 6;
    #pragma unroll
    for (int j = 0; j < 8; ++j) {
      const int kg = iekc * 32 + ksub * 8 + j;
      const float wv = Wi[(size_t)kg * 3072 + gcol];
      const unsigned hb = f2bf_bits(wv);
      bih[nt][j] = (short)hb;
      bil[nt][j] = (short)f2bf_bits(wv - bfbits2f(hb));
    }
  }

  const float* ubase = u + (size_t)(r0 + rloc) * 131072 + iekc * 32 + ksub * 8;

  // ---- ie math from prefetched registers ----
  auto ie_math = [&](float4 xa_, float4 xb_) {
    const float xv[8] = {xa_.x, xa_.y, xa_.z, xa_.w, xb_.x, xb_.y, xb_.z, xb_.w};
    short8 ah, al;
    #pragma unroll
    for (int j = 0; j < 8; ++j) {
      const unsigned hb = f2bf_bits(xv[j]);
      ah[j] = (short)hb;
      al[j] = (short)f2bf_bits(xv[j] - bfbits2f(hb));
    }
    f32x4 acc[3];
    #pragma unroll
    for (int nt = 0; nt < 3; ++nt) { acc[nt][0]=0.f; acc[nt][1]=0.f; acc[nt][2]=0.f; acc[nt][3]=0.f; }
    #pragma unroll
    for (int nt = 0; nt < 3; ++nt) {
      acc[nt] = __builtin_amdgcn_mfma_f32_16x16x32_bf16(ah, bih[nt], acc[nt], 0, 0, 0);
      acc[nt] = __builtin_amdgcn_mfma_f32_16x16x32_bf16(ah, bil[nt], acc[nt], 0, 0, 0);
      acc[nt] = __builtin_amdgcn_mfma_f32_16x16x32_bf16(al, bih[nt], acc[nt], 0, 0, 0);
    }
    if (lane < 32) {
      const int rb = (lane >> 4) * 4;
      #pragma unroll
      for (int nt = 0; nt < 3; ++nt)
        #pragma unroll
        for (int i = 0; i < 4; ++i)
          ie_part[iekc * 768 + (rb + i) * 96 + (ienh * 3 + nt) * 16 + colf] = acc[nt][i];
    }
  };

  // ---- ie(0) ----
  {
    const float4 xa0 = *(const float4*)ubase;
    const float4 xb0 = *(const float4*)(ubase + 4);
    ie_math(xa0, xb0);
  }

  const bool active = (lane & 8) == 0;   // fragment rows 8-15 are padding

  for (int st = 0; st < LSTEP; ++st) {
    const unsigned long long* __restrict__ scurF = (st & 1) ? stateFB : stateFA;
    unsigned long long* __restrict__ snxtF       = (st & 1) ? stateFA : stateFB;
    const unsigned long long* __restrict__ scurS = (st & 1) ? stateSB : stateSA;
    unsigned long long* __restrict__ snxtS       = (st & 1) ? stateSA : stateSB;

    // ======== phase 1: dual-path poll-with-payload, unpack, MFMA ========
    {
      const unsigned tag = (unsigned)(st + 1);
      const size_t eoff = (size_t)(r0 + rloc) * 512 + w * 64 + ksub * 8;
      u32x4 p0 = {0,0,0,0}, p1 = {0,0,0,0}, p2 = {0,0,0,0}, p3 = {0,0,0,0};
      u32x4 p4 = {0,0,0,0}, p5 = {0,0,0,0}, p6 = {0,0,0,0}, p7 = {0,0,0,0};
      if (active) {
#define READ8(PTR, FLAG, OKVAR)                                                                              \
        {                                                                                                    \
          asm volatile("global_load_dwordx4 %0, %1, off " FLAG            : "=&v"(p0) : "v"(PTR) : "memory"); \
          asm volatile("global_load_dwordx4 %0, %1, off offset:16 " FLAG  : "=&v"(p1) : "v"(PTR) : "memory"); \
          asm volatile("global_load_dwordx4 %0, %1, off offset:32 " FLAG  : "=&v"(p2) : "v"(PTR) : "memory"); \
          asm volatile("global_load_dwordx4 %0, %1, off offset:48 " FLAG  : "=&v"(p3) : "v"(PTR) : "memory"); \
          asm volatile("global_load_dwordx4 %0, %1, off offset:256 " FLAG : "=&v"(p4) : "v"(PTR) : "memory"); \
          asm volatile("global_load_dwordx4 %0, %1, off offset:272 " FLAG : "=&v"(p5) : "v"(PTR) : "memory"); \
          asm volatile("global_load_dwordx4 %0, %1, off offset:288 " FLAG : "=&v"(p6) : "v"(PTR) : "memory"); \
          asm volatile("global_load_dwordx4 %0, %1, off offset:304 " FLAG : "=&v"(p7) : "v"(PTR) : "memory"); \
          asm volatile("s_waitcnt vmcnt(0)" ::: "memory");                                                   \
          __builtin_amdgcn_sched_barrier(0);  /* rule #18: compare AFTER waitcnt */                          \
          OKVAR = p0[1] >= tag && p0[3] >= tag && p1[1] >= tag && p1[3] >= tag                               \
               && p2[1] >= tag && p2[3] >= tag && p3[1] >= tag && p3[3] >= tag                               \
               && p4[1] >= tag && p4[3] >= tag && p5[1] >= tag && p5[3] >= tag                               \
               && p6[1] >= tag && p6[3] >= tag && p7[1] >= tag && p7[3] >= tag;                              \
        }
        bool got = false;
        if (fastmode) {
          const unsigned long long* baseF = scurF + eoff;
          int tries = 0;
          bool ok;
          do {
            READ8(baseF, "nt", ok)
            if (__all(ok)) { got = true; break; }
          } while (++tries < FAST_TRIES);
          if (!got) fastmode = false;   // deterministic, permanent — no deadlock
        }
        if (!got) {
          const unsigned long long* baseS = scurS + eoff;
          for (;;) {
            bool ok;
            READ8(baseS, "sc1", ok)
            if (__all(ok)) break;
            __builtin_amdgcn_s_sleep(1);
          }
        }
#undef READ8
      }
      __builtin_amdgcn_sched_barrier(0);
      short8 ah[2], al[2];
      ah[0][0] = (short)(p0[0] & 0xffffu); al[0][0] = (short)(p0[0] >> 16);
      ah[0][1] = (short)(p0[2] & 0xffffu); al[0][1] = (short)(p0[2] >> 16);
      ah[0][2] = (short)(p1[0] & 0xffffu); al[0][2] = (short)(p1[0] >> 16);
      ah[0][3] = (short)(p1[2] & 0xffffu); al[0][3] = (short)(p1[2] >> 16);
      ah[0][4] = (short)(p2[0] & 0xffffu); al[0][4] = (short)(p2[0] >> 16);
      ah[0][5] = (short)(p2[2] & 0xffffu); al[0][5] = (short)(p2[2] >> 16);
      ah[0][6] = (short)(p3[0] & 0xffffu); al[0][6] = (short)(p3[0] >> 16);
      ah[0][7] = (short)(p3[2] & 0xffffu); al[0][7] = (short)(p3[2] >> 16);
      ah[1][0] = (short)(p4[0] & 0xffffu); al[1][0] = (short)(p4[0] >> 16);
      ah[1][1] = (short)(p4[2] & 0xffffu); al[1][1] = (short)(p4[2] >> 16);
      ah[1][2] = (short)(p5[0] & 0xffffu); al[1][2] = (short)(p5[0] >> 16);
      ah[1][3] = (short)(p5[2] & 0xffffu); al[1][3] = (short)(p5[2] >> 16);
      ah[1][4] = (short)(p6[0] & 0xffffu); al[1][4] = (short)(p6[0] >> 16);
      ah[1][5] = (short)(p6[2] & 0xffffu); al[1][5] = (short)(p6[2] >> 16);
      ah[1][6] = (short)(p7[0] & 0xffffu); al[1][6] = (short)(p7[0] >> 16);
      ah[1][7] = (short)(p7[2] & 0xffffu); al[1][7] = (short)(p7[2] >> 16);
      f32x4 acc[5];
      #pragma unroll
      for (int nt = 0; nt < 5; ++nt) { acc[nt][0]=0.f; acc[nt][1]=0.f; acc[nt][2]=0.f; acc[nt][3]=0.f; }
      #pragma unroll
      for (int nt = 0; nt < 5; ++nt)
        #pragma unroll
        for (int kt = 0; kt < 2; ++kt) {
          acc[nt] = __builtin_amdgcn_mfma_f32_16x16x32_bf16(ah[kt], bh[nt][kt], acc[nt], 0, 0, 0);
          acc[nt] = __builtin_amdgcn_mfma_f32_16x16x32_bf16(ah[kt], bl[nt][kt], acc[nt], 0, 0, 0);
          acc[nt] = __builtin_amdgcn_mfma_f32_16x16x32_bf16(al[kt], bh[nt][kt], acc[nt], 0, 0, 0);
        }
      if (lane < 32) {
        const int rb = (lane >> 4) * 4;
        #pragma unroll
        for (int nt = 0; nt < 5; ++nt)
          #pragma unroll
          for (int i = 0; i < 4; ++i)
            part_s[(w * 8 + rb + i) * 80 + nt * 16 + colf] = acc[nt][i];
      }
    }
    __syncthreads();   // sync #1 — part_s/ie_part complete for step st

    // ---- prefetch u(st+1) ----
    float4 xa = {0.f, 0.f, 0.f, 0.f}, xb = {0.f, 0.f, 0.f, 0.f};
    if (st + 1 < LSTEP) {
      const float* up = ubase + (size_t)(st + 1) * 128;
      xa = *(const float4*)up;
      xb = *(const float4*)(up + 4);
    }

    // ======== phase 2: fused reduce + gates + dual tagged publish ========
    if (tid < 128) {
      const int r = tid >> 4, j16 = tid & 15;
      float m[5];
      #pragma unroll
      for (int g = 0; g < 5; ++g) {
        float v = bm_s[j16 * 5 + g];
        #pragma unroll
        for (int kh = 0; kh < 8; ++kh) v += part_s[kh * 640 + r * 80 + j16 * 5 + g];
        m[g] = v;
      }
      float iacc[6];
      #pragma unroll
      for (int g = 0; g < 6; ++g) {
        float v = bi_s[j16 * 6 + g];
        #pragma unroll
        for (int kc = 0; kc < 4; ++kc) v += ie_part[kc * 768 + r * 96 + j16 * 6 + g];
        iacc[g] = v;
      }
      const float hf = hf_own[tid];
      const float hs = hs_own[tid];
      const float a = 1.f + ftanh(iacc[0] + m[0]);
      const float b = 1.5f * (1.f + ftanh(iacc[1] + m[1]));
      const float c = 0.3f + 0.7f * fsig(iacc[2] + m[2]);
      const float d = 0.03f * fsig(iacc[3] + m[3]);
      const float e = 1.f + fsig(iacc[4] + m[4]);
      const float hfn_v = (1.f - c) * hf + c * ftanh(iacc[5] + (a + b * hf * hf - hs) * hf);
      const float eh  = e * hf;
      const float eh2 = eh * eh;
      const float hsn_v = hs * (1.f - d) + d * eh2 * eh2;
      hf_own[tid] = hfn_v;
      hs_own[tid] = hsn_v;
      const unsigned hb = f2bf_bits(hfn_v);
      const unsigned lb = f2bf_bits(hfn_v - bfbits2f(hb));
      u32x2 pr; pr[0] = hb | (lb << 16); pr[1] = (unsigned)(st + 2);
      const size_t eo = (size_t)(r0 + r) * 512 + j0 + j16;
      asm volatile("global_store_dwordx2 %0, %1, off"     :: "v"(snxtF + eo), "v"(pr) : "memory");
      asm volatile("global_store_dwordx2 %0, %1, off sc1" :: "v"(snxtS + eo), "v"(pr) : "memory");
      out[(size_t)(r0 + r) * 524288 + (size_t)st * 512 + j0 + j16] = hfn_v;
      if (st == LSTEP - 1)
        out[(size_t)33554432 + (size_t)(r0 + r) * 512 + j0 + j16] = hfn_v;
    }
    __syncthreads();   // sync #2 — part_s/ie_part free for reuse
    if (st + 1 < LSTEP) ie_math(xa, xb);  // R10 placement: useful publish->poll delay
  }
}

extern "C" void kernel_launch(void* const* d_in, const int* in_sizes, int n_in,
                              void* d_out, int out_size, void* d_ws, size_t ws_size,
                              hipStream_t stream) {
  (void)in_sizes; (void)n_in; (void)out_size; (void)ws_size;
  const float* u  = (const float*)d_in[0];
  const float* h0 = (const float*)d_in[1];
  const float* Wi = (const float*)d_in[2];
  const float* bi = (const float*)d_in[3];
  const float* Wm = (const float*)d_in[4];
  const float* bm = (const float*)d_in[5];
  float* out = (float*)d_out;
  unsigned* xcctab = (unsigned*)d_ws;                        // [0, 1024)
  char* sb = (char*)d_ws + 4096;
  unsigned long long* stateFA = (unsigned long long*)(sb);
  unsigned long long* stateFB = (unsigned long long*)(sb + 262144);
  unsigned long long* stateSA = (unsigned long long*)(sb + 2 * 262144);
  unsigned long long* stateSB = (unsigned long long*)(sb + 3 * 262144);
  hipMemsetAsync(d_ws, 0, 4096 + 4 * 262144, stream);  // xcctab + all tags
  hipLaunchKernelGGL(fused_scan, dim3(NWG), dim3(NTH), 0, stream,
                     u, h0, Wi, bi, Wm, bm, out,
                     stateFA, stateFB, stateSA, stateSB, xcctab);
}